// Round 7
// baseline (274.616 us; speedup 1.0000x reference)
//
#include <hip/hip_runtime.h>
#include <cstdint>
#include <cstddef>

// Problem constants (MultiHeadAttention: B=4, T=2048, d_model=1024, H=16, hd=64)
#define D_MODEL 1024
#define SEQQ    2048
#define NBATCH  4
#define NHEAD   16
#define HDIM    64
#define MTOT    (NBATCH * SEQQ)   // 8192 rows

typedef __attribute__((ext_vector_type(8))) short short8;   // 8 x bf16 (4 VGPRs) — MFMA A/B frag
typedef __attribute__((ext_vector_type(4))) float floatx4;  // MFMA C/D frag
typedef unsigned short u16;                                  // bf16 bits

__device__ __forceinline__ u16 f2bf(float f) {
  union { float f; uint32_t u; } a; a.f = f;
  uint32_t u = a.u;
  u += 0x7fffu + ((u >> 16) & 1u);   // RN-even
  return (u16)(u >> 16);
}

__device__ __forceinline__ floatx4 mfma16(short8 a, short8 b, floatx4 c) {
  return __builtin_amdgcn_mfma_f32_16x16x32_bf16(a, b, c, 0, 0, 0);
}

// async global->LDS, 16B per lane. LDS dest = wave-uniform base + lane*16.
__device__ __forceinline__ void load_lds16(const void* g, void* l) {
  __builtin_amdgcn_global_load_lds(
      (const __attribute__((address_space(1))) uint32_t*)g,
      (__attribute__((address_space(3))) uint32_t*)l, 16, 0, 0);
}

// ---------------------------------------------------------------- fused casts f32->bf16
// blocks [0, 8192): X. blocks [8192, 12288): weights, 1024 blocks each.
__global__ __launch_bounds__(256) void k_cast_all(
    const float* __restrict__ X, const float* __restrict__ w0,
    const float* __restrict__ w1, const float* __restrict__ w2,
    const float* __restrict__ w3,
    u16* __restrict__ xb, u16* __restrict__ y0, u16* __restrict__ y1,
    u16* __restrict__ y2, u16* __restrict__ y3) {
  const int bx = blockIdx.x;
  const float* src; u16* dst; int i;
  if (bx < 8192) {
    src = X; dst = xb; i = (bx * 256 + threadIdx.x) * 4;
  } else {
    const int w = (bx - 8192) >> 10;
    src = (w == 0) ? w0 : (w == 1) ? w1 : (w == 2) ? w2 : w3;
    dst = (w == 0) ? y0 : (w == 1) ? y1 : (w == 2) ? y2 : y3;
    i = (((bx - 8192) & 1023) * 256 + threadIdx.x) * 4;
  }
  float4 v = *(const float4*)(src + i);
  ushort4 o;
  o.x = f2bf(v.x); o.y = f2bf(v.y); o.z = f2bf(v.z); o.w = f2bf(v.w);
  *(ushort4*)(dst + i) = o;
}

// ---------------------------------------------------------------- GEMM  C = A @ B^T (+bias)
// ascaleQ: extra scale on the z==0 output (folds 1/sqrt(hd)*log2e into Q).
// z==2 (V projection): epilogue writes TRANSPOSED into Vt [bh][64][2048].
__global__ __launch_bounds__(256) void k_gemm_bt(
    const u16* __restrict__ A,
    const u16* __restrict__ B0, const u16* __restrict__ B1, const u16* __restrict__ B2,
    void* __restrict__ C0, void* __restrict__ C1, u16* __restrict__ VtOut,
    const float* __restrict__ bias, int M, int N, int K, int f32out, float ascaleQ) {
  __shared__ __align__(16) u16 As[128 * 64];
  __shared__ __align__(16) u16 Bs[128 * 64];
  const int tid = threadIdx.x;
  const int lane = tid & 63, wave = tid >> 6;
  const int quad = lane >> 4, l15 = lane & 15;
  const int m0 = blockIdx.y * 128, n0 = blockIdx.x * 128;
  const int wr = wave >> 1, wc = wave & 1;
  const u16* Bm = (blockIdx.z == 0) ? B0 : (blockIdx.z == 1 ? B1 : B2);
  void* Cm = (blockIdx.z == 0) ? C0 : C1;
  const float ascale = (blockIdx.z == 0) ? ascaleQ : 1.0f;

  floatx4 acc[4][4];
#pragma unroll
  for (int i = 0; i < 4; ++i)
#pragma unroll
    for (int j = 0; j < 4; ++j) acc[i][j] = (floatx4){0.f, 0.f, 0.f, 0.f};

  const int srow = tid >> 3;                       // 0..31
  const int scolx = ((tid & 7) * 8) ^ ((srow & 7) * 8);  // swizzled source column
  const u16* Ag = A + (size_t)(m0 + srow) * K + scolx;
  const u16* Bg = Bm + (size_t)(n0 + srow) * K + scolx;

  for (int kt = 0; kt < K; kt += 64) {
    __syncthreads();
#pragma unroll
    for (int p = 0; p < 4; ++p) {
      load_lds16(Ag + (size_t)(p * 32) * K + kt, &As[p * 2048 + wave * 512]);
      load_lds16(Bg + (size_t)(p * 32) * K + kt, &Bs[p * 2048 + wave * 512]);
    }
    __syncthreads();

    short8 af[2][4], bfg[2][4];
#pragma unroll
    for (int ks = 0; ks < 2; ++ks) {
      const int kkx = (ks * 32 + quad * 8) ^ ((l15 & 7) * 8);
#pragma unroll
      for (int i = 0; i < 4; ++i) {
        af[ks][i]  = *(const short8*)&As[(wr * 64 + i * 16 + l15) * 64 + kkx];
        bfg[ks][i] = *(const short8*)&Bs[(wc * 64 + i * 16 + l15) * 64 + kkx];
      }
    }
#pragma unroll
    for (int ks = 0; ks < 2; ++ks)
#pragma unroll
      for (int mi = 0; mi < 4; ++mi)
#pragma unroll
        for (int ni = 0; ni < 4; ++ni)
          acc[mi][ni] = mfma16(af[ks][mi], bfg[ks][ni], acc[mi][ni]);
  }

  // Epilogue. C/D layout: col = lane&15, row = quad*4 + reg (m89-verified).
  if (blockIdx.z == 2) {
    // transposed V write: Vt[(b*16+h)*64 + d][t], 4 regs = t..t+3 contiguous
#pragma unroll
    for (int mi = 0; mi < 4; ++mi) {
#pragma unroll
      for (int ni = 0; ni < 4; ++ni) {
        const int row = m0 + wr * 64 + mi * 16 + quad * 4;   // token
        const int col = n0 + wc * 64 + ni * 16 + l15;        // channel
        const int b = row >> 11, t = row & 2047;
        const int h = col >> 6, d = col & 63;
        ushort4 pk;
        pk.x = f2bf(acc[mi][ni][0]); pk.y = f2bf(acc[mi][ni][1]);
        pk.z = f2bf(acc[mi][ni][2]); pk.w = f2bf(acc[mi][ni][3]);
        *(ushort4*)(VtOut + (((size_t)(b * 16 + h) * 64 + d) * SEQQ + t)) = pk;
      }
    }
    return;
  }
#pragma unroll
  for (int mi = 0; mi < 4; ++mi) {
#pragma unroll
    for (int ni = 0; ni < 4; ++ni) {
      const int row = m0 + wr * 64 + mi * 16 + quad * 4;
      const int col = n0 + wc * 64 + ni * 16 + l15;
      const float bv = bias ? bias[col] : 0.f;
#pragma unroll
      for (int r = 0; r < 4; ++r) {
        const float v = acc[mi][ni][r] * ascale + bv;
        if (f32out) ((float*)Cm)[(size_t)(row + r) * N + col] = v;
        else        ((u16*)Cm)[(size_t)(row + r) * N + col] = f2bf(v);
      }
    }
  }
}

// ---------------------------------------------------------------- flash attention
// ROUND-7: 8-wave blocks (r6 structure, measured 80.1us) + in-register P
// redistribution (permlane quad-transpose, r3/r4-correctness-proven) replacing
// the Ps LDS bounce. REGIME RATIONALE: r6 PMC shows LDS is the widest pipe
// (~60% util: 16 waves x {16 ds_read_b128 + Ps write/read} per CU-iter) while
// VALUBusy fell to 25% — opposite of r4's regime (VALU 49%) where permlane
// lost. Moving P's transpose to the slack VALU pipe cuts LDS traffic ~1/3 and
// kills the 2.16M bank conflicts (r4 evidence: conflicts==0 with permlane).
// Also deletes Ps (LDS 64->32KiB) and the explicit lgkmcnt(0) drain.
__device__ __forceinline__ short8 mk8(uint32_t a, uint32_t b, uint32_t c, uint32_t d) {
  union { uint32_t u[4]; short8 s; } t;
  t.u[0] = a; t.u[1] = b; t.u[2] = c; t.u[3] = d;
  return t.s;
}

// exp2 + pack one side's S^T tiles -> denominator + 8 bf16x2 words (in regs)
__device__ __forceinline__ void softmax_reg(
    const floatx4 (&st)[4], float& lp, uint32_t (&w)[4][2]) {
#pragma unroll
  for (int ni = 0; ni < 4; ++ni) {
    const float p0 = __builtin_amdgcn_exp2f(st[ni][0]);
    const float p1 = __builtin_amdgcn_exp2f(st[ni][1]);
    const float p2 = __builtin_amdgcn_exp2f(st[ni][2]);
    const float p3 = __builtin_amdgcn_exp2f(st[ni][3]);
    lp += (p0 + p1) + (p2 + p3);
    // w[ni][0] = keys(ni*16+quad*4 +0,+1), w[ni][1] = (+2,+3), packed bf16x2
    w[ni][0] = __builtin_amdgcn_perm(__float_as_uint(p1), __float_as_uint(p0), 0x07060302u);
    w[ni][1] = __builtin_amdgcn_perm(__float_as_uint(p3), __float_as_uint(p2), 0x07060302u);
  }
}

// build PV A-operand (keys kc*32+quad*8+{0..7} at q=l15) from the 4 quads'
// packed tiles via the quad-transpose swap network (r2-derived, r3/r4-proven):
//   y=w[2kc][s], z=w[2kc+1][s];
//   permlane32_swap(y,z): y'=(y@0,y@1,z@0,z@1), z'=(y@2,y@3,z@2,z@3)
//   permlane16_swap(y',z'): y''=(y@0,y@2,z@0,z@2), z''=(y@1,y@3,z@1,z@3)
__device__ __forceinline__ short8 pf_prep(const uint32_t (&w)[4][2], int kc) {
  uint32_t y0 = w[2 * kc][0], z0 = w[2 * kc + 1][0];
  asm("v_permlane32_swap_b32 %0, %1" : "+v"(y0), "+v"(z0));
  asm("v_permlane16_swap_b32 %0, %1" : "+v"(y0), "+v"(z0));
  uint32_t y1 = w[2 * kc][1], z1 = w[2 * kc + 1][1];
  asm("v_permlane32_swap_b32 %0, %1" : "+v"(y1), "+v"(z1));
  asm("v_permlane16_swap_b32 %0, %1" : "+v"(y1), "+v"(z1));
  return mk8(y0, y1, z0, z1);
}

__global__ __launch_bounds__(512) void k_attn(
    const u16* __restrict__ Q, const u16* __restrict__ Kg,
    const u16* __restrict__ Vt, u16* __restrict__ O) {
  __shared__ __align__(16) u16 Ks[2][64 * 64];
  __shared__ __align__(16) u16 Vs[2][64 * 64];
  const int tid = threadIdx.x, lane = tid & 63, wave = tid >> 6;
  const int quad = lane >> 4, l15 = lane & 15;

  // balanced (g, bh) derivation: CU c hosts blocks c and c+256 -> g and 7-g
  // -> per-CU loop total (32-2g)+(18+2g) = 50, constant.
  const int lin = blockIdx.x;
  const int c = lin & 255, k2 = lin >> 8;
  const int g = k2 ? (7 - (c & 7)) : (c & 7);       // pair-group 0..7
  const int bh = (c >> 3) | (k2 << 5);              // 0..63
  const int b = bh >> 4, h = bh & 15;

  const int wgrp = wave >> 2, wsub = wave & 3;
  const int a = 2 * g + wgrp;                // this wave's pair index 0..15
  const int qwA = 64 * a + wsub * 16;
  const int qwB = SEQQ - 64 * (a + 1) + wsub * 16;
  const int nT = 32 - 2 * g;                 // block loop count (= wgrp0's range)
  const int lastB = 31 - a;                  // B diag iteration (own range-1)

  const u16* kbase = Kg + (size_t)(b * SEQQ) * D_MODEL + h * HDIM;
  const u16* vbase = Vt + (size_t)bh * (HDIM * SEQQ);

  const int srow = tid >> 3;                            // 0..63 (512 threads)
  const int scol = ((tid & 7) * 8) ^ ((srow & 7) * 8);  // swizzled col 0..63

  // issue first staging before anything else: each wave stages 8 rows of K, V
  {
    load_lds16(kbase + (size_t)srow * D_MODEL + scol, &Ks[0][wave * 512]);
    load_lds16(vbase + (size_t)srow * SEQQ + scol,    &Vs[0][wave * 512]);
  }

  // Q fragments ([idx=l15][k=quad*8+j]); Q pre-scaled by 1/sqrt(hd)*log2e.
  short8 qfA[2], qfB[2];
  {
    const u16* qa = Q + (size_t)(b * SEQQ + qwA + l15) * D_MODEL + h * HDIM;
    const u16* qb = Q + (size_t)(b * SEQQ + qwB + l15) * D_MODEL + h * HDIM;
#pragma unroll
    for (int ks = 0; ks < 2; ++ks) {
      qfA[ks] = *(const short8*)(qa + ks * 32 + quad * 8);
      qfB[ks] = *(const short8*)(qb + ks * 32 + quad * 8);
    }
  }

  floatx4 accA[4], accB[4];
  float lAp = 0.f, lBp = 0.f;     // per-lane partial softmax denominators
#pragma unroll
  for (int i = 0; i < 4; ++i) {
    accA[i] = (floatx4){0.f, 0.f, 0.f, 0.f};
    accB[i] = (floatx4){0.f, 0.f, 0.f, 0.f};
  }

  for (int t = 0; t < nT; ++t) {
    const int cur = t & 1;
    __syncthreads();   // drains stage(t) (vmcnt) + all reads of buf[cur^1]
    if (t + 1 < nT) {  // prefetch next tile into the other buffer
      const int kt1 = (t + 1) * 64, nxt = cur ^ 1;
      load_lds16(kbase + (size_t)(kt1 + srow) * D_MODEL + scol, &Ks[nxt][wave * 512]);
      load_lds16(vbase + (size_t)srow * SEQQ + kt1 + scol,      &Vs[nxt][wave * 512]);
    }
    const int kt = t * 64;

    // K fragments ([key=l15][d=quad*8+j]), shared by both q-tiles of this wave
    short8 kf[4][2];
#pragma unroll
    for (int ni = 0; ni < 4; ++ni)
#pragma unroll
      for (int ks = 0; ks < 2; ++ks)
        kf[ni][ks] = *(const short8*)&Ks[cur][(ni * 16 + l15) * 64 +
                                            ((ks * 32 + quad * 8) ^ ((l15 & 7) * 8))];
    // V fragments ([d=l15][key=quad*8+j])
    short8 vf[2][4];
#pragma unroll
    for (int kc = 0; kc < 2; ++kc)
#pragma unroll
      for (int di = 0; di < 4; ++di)
        vf[kc][di] = *(const short8*)&Vs[cur][(di * 16 + l15) * 64 +
                                             ((kc * 32 + quad * 8) ^ ((l15 & 7) * 8))];

    const bool doA = (t <= a);       // wave-uniform
    const bool doB = (t <= lastB);   // wave-uniform (false only on wgrp1's last iter)
    uint32_t wA[4][2], wB[4][2];
    if (doA) {
      floatx4 st[4];   // S^T: row=key (quad*4+r, tile ni), col=q (l15)
#pragma unroll
      for (int ni = 0; ni < 4; ++ni) {
        floatx4 s = (floatx4){0.f, 0.f, 0.f, 0.f};
        s = mfma16(kf[ni][0], qfA[0], s);
        s = mfma16(kf[ni][1], qfA[1], s);
        st[ni] = s;
      }
      if (t == a) {   // diagonal tile of A: mask key > q
        const int qg = qwA + l15;
#pragma unroll
        for (int ni = 0; ni < 4; ++ni) {
          const int kg = kt + ni * 16 + quad * 4;
#pragma unroll
          for (int r = 0; r < 4; ++r)
            if (kg + r > qg) st[ni][r] = -1e30f;
        }
      }
      softmax_reg(st, lAp, wA);
    }
    if (doB) {
      floatx4 st[4];
#pragma unroll
      for (int ni = 0; ni < 4; ++ni) {
        floatx4 s = (floatx4){0.f, 0.f, 0.f, 0.f};
        s = mfma16(kf[ni][0], qfB[0], s);
        s = mfma16(kf[ni][1], qfB[1], s);
        st[ni] = s;
      }
      if (t == lastB) {   // diagonal tile of B
        const int qg = qwB + l15;
#pragma unroll
        for (int ni = 0; ni < 4; ++ni) {
          const int kg = kt + ni * 16 + quad * 4;
#pragma unroll
          for (int r = 0; r < 4; ++r)
            if (kg + r > qg) st[ni][r] = -1e30f;
        }
      }
      softmax_reg(st, lBp, wB);
    }
    // PV: pf built in-register (permlane quad-transpose); vf shared by A/B
#pragma unroll
    for (int kc = 0; kc < 2; ++kc) {
      if (doA) {
        const short8 pfA = pf_prep(wA, kc);
#pragma unroll
        for (int di = 0; di < 4; ++di)
          accA[di] = mfma16(pfA, vf[kc][di], accA[di]);
      }
      if (doB) {
        const short8 pfB = pf_prep(wB, kc);
#pragma unroll
        for (int di = 0; di < 4; ++di)
          accB[di] = mfma16(pfB, vf[kc][di], accB[di]);
      }
    }
  }

  // l reduce: across the 4 quad groups (same l15) -> every lane holds l(q=l15)
  lAp += __shfl_xor(lAp, 16); lAp += __shfl_xor(lAp, 32);
  lBp += __shfl_xor(lBp, 16); lBp += __shfl_xor(lBp, 32);

  // epilogue: O rows q=quad*4+r, cols d=di*16+l15; l for row via shfl
  {
    u16* orow = O + (size_t)(b * SEQQ + qwA + quad * 4) * D_MODEL + h * HDIM + l15;
#pragma unroll
    for (int r = 0; r < 4; ++r) {
      const float inv = 1.0f / __shfl(lAp, quad * 4 + r, 16);
#pragma unroll
      for (int di = 0; di < 4; ++di)
        orow[(size_t)r * D_MODEL + di * 16] = f2bf(accA[di][r] * inv);
    }
  }
  {
    u16* orow = O + (size_t)(b * SEQQ + qwB + quad * 4) * D_MODEL + h * HDIM + l15;
#pragma unroll
    for (int r = 0; r < 4; ++r) {
      const float inv = 1.0f / __shfl(lBp, quad * 4 + r, 16);
#pragma unroll
      for (int di = 0; di < 4; ++di)
        orow[(size_t)r * D_MODEL + di * 16] = f2bf(accB[di][r] * inv);
    }
  }
}

// ---------------------------------------------------------------- launch
extern "C" void kernel_launch(void* const* d_in, const int* in_sizes, int n_in,
                              void* d_out, int out_size, void* d_ws, size_t ws_size,
                              hipStream_t stream) {
  const float* X  = (const float*)d_in[0];
  const float* Wq = (const float*)d_in[1];
  const float* Wk = (const float*)d_in[2];
  const float* Wv = (const float*)d_in[3];
  const float* Wo = (const float*)d_in[4];
  const float* bo = (const float*)d_in[5];
  float* out = (float*)d_out;

  u16* ws = (u16*)d_ws;
  const size_t NE = (size_t)MTOT * D_MODEL;    // 8,388,608
  u16* Xb  = ws;
  u16* Qb  = Xb + NE;
  u16* Kb  = Qb + NE;
  u16* Vt  = Kb + NE;          // V projection written directly transposed
  u16* Cb  = Vt + NE;
  u16* Wqb = Cb + NE;
  u16* Wkb = Wqb + (size_t)D_MODEL * D_MODEL;
  u16* Wvb = Wkb + (size_t)D_MODEL * D_MODEL;
  u16* Wob = Wvb + (size_t)D_MODEL * D_MODEL;

  const float SCL2E = 0.18033688f;   // (1/sqrt(64)) * log2(e), folded into Q

  // 1. all casts in one launch
  k_cast_all<<<12288, 256, 0, stream>>>(X, Wq, Wk, Wv, Wo, Xb, Wqb, Wkb, Wvb, Wob);

  // 2. fused QKV projections (Q pre-scaled; V written transposed into Vt)
  k_gemm_bt<<<dim3(D_MODEL / 128, MTOT / 128, 3), 256, 0, stream>>>(
      Xb, Wqb, Wkb, Wvb, Qb, Kb, Vt, nullptr, MTOT, D_MODEL, D_MODEL, 0, SCL2E);

  // 3. causal flash attention, 8-wave blocks, balanced 1D grid -> Cb [8192][1024]
  k_attn<<<512, 512, 0, stream>>>(Qb, Kb, Vt, Cb);

  // 4. output projection + bias, f32 out
  k_gemm_bt<<<dim3(D_MODEL / 128, MTOT / 128, 1), 256, 0, stream>>>(
      Cb, Wob, Wob, Wob, out, out, nullptr, bo, MTOT, D_MODEL, D_MODEL, 1, 1.0f);
}

// Round 8
// 271.426 us; speedup vs baseline: 1.0118x; 1.0118x over previous
//
#include <hip/hip_runtime.h>
#include <cstdint>
#include <cstddef>

// Problem constants (MultiHeadAttention: B=4, T=2048, d_model=1024, H=16, hd=64)
#define D_MODEL 1024
#define SEQQ    2048
#define NBATCH  4
#define NHEAD   16
#define HDIM    64
#define MTOT    (NBATCH * SEQQ)   // 8192 rows

typedef __attribute__((ext_vector_type(8))) short short8;   // 8 x bf16 (4 VGPRs) — MFMA A/B frag
typedef __attribute__((ext_vector_type(4))) float floatx4;  // MFMA C/D frag
typedef unsigned short u16;                                  // bf16 bits

__device__ __forceinline__ u16 f2bf(float f) {
  union { float f; uint32_t u; } a; a.f = f;
  uint32_t u = a.u;
  u += 0x7fffu + ((u >> 16) & 1u);   // RN-even
  return (u16)(u >> 16);
}

__device__ __forceinline__ floatx4 mfma16(short8 a, short8 b, floatx4 c) {
  return __builtin_amdgcn_mfma_f32_16x16x32_bf16(a, b, c, 0, 0, 0);
}

// async global->LDS, 16B per lane. LDS dest = wave-uniform base + lane*16.
__device__ __forceinline__ void load_lds16(const void* g, void* l) {
  __builtin_amdgcn_global_load_lds(
      (const __attribute__((address_space(1))) uint32_t*)g,
      (__attribute__((address_space(3))) uint32_t*)l, 16, 0, 0);
}

// ---------------------------------------------------------------- fused casts f32->bf16
// blocks [0, 8192): X. blocks [8192, 12288): weights, 1024 blocks each.
__global__ __launch_bounds__(256) void k_cast_all(
    const float* __restrict__ X, const float* __restrict__ w0,
    const float* __restrict__ w1, const float* __restrict__ w2,
    const float* __restrict__ w3,
    u16* __restrict__ xb, u16* __restrict__ y0, u16* __restrict__ y1,
    u16* __restrict__ y2, u16* __restrict__ y3) {
  const int bx = blockIdx.x;
  const float* src; u16* dst; int i;
  if (bx < 8192) {
    src = X; dst = xb; i = (bx * 256 + threadIdx.x) * 4;
  } else {
    const int w = (bx - 8192) >> 10;
    src = (w == 0) ? w0 : (w == 1) ? w1 : (w == 2) ? w2 : w3;
    dst = (w == 0) ? y0 : (w == 1) ? y1 : (w == 2) ? y2 : y3;
    i = (((bx - 8192) & 1023) * 256 + threadIdx.x) * 4;
  }
  float4 v = *(const float4*)(src + i);
  ushort4 o;
  o.x = f2bf(v.x); o.y = f2bf(v.y); o.z = f2bf(v.z); o.w = f2bf(v.w);
  *(ushort4*)(dst + i) = o;
}

// ---------------------------------------------------------------- GEMM  C = A @ B^T (+bias)
// ascaleQ: extra scale on the z==0 output (folds 1/sqrt(hd)*log2e into Q).
// z==2 (V projection): epilogue writes TRANSPOSED into Vt [bh][64][2048].
__global__ __launch_bounds__(256) void k_gemm_bt(
    const u16* __restrict__ A,
    const u16* __restrict__ B0, const u16* __restrict__ B1, const u16* __restrict__ B2,
    void* __restrict__ C0, void* __restrict__ C1, u16* __restrict__ VtOut,
    const float* __restrict__ bias, int M, int N, int K, int f32out, float ascaleQ) {
  __shared__ __align__(16) u16 As[128 * 64];
  __shared__ __align__(16) u16 Bs[128 * 64];
  const int tid = threadIdx.x;
  const int lane = tid & 63, wave = tid >> 6;
  const int quad = lane >> 4, l15 = lane & 15;
  const int m0 = blockIdx.y * 128, n0 = blockIdx.x * 128;
  const int wr = wave >> 1, wc = wave & 1;
  const u16* Bm = (blockIdx.z == 0) ? B0 : (blockIdx.z == 1 ? B1 : B2);
  void* Cm = (blockIdx.z == 0) ? C0 : C1;
  const float ascale = (blockIdx.z == 0) ? ascaleQ : 1.0f;

  floatx4 acc[4][4];
#pragma unroll
  for (int i = 0; i < 4; ++i)
#pragma unroll
    for (int j = 0; j < 4; ++j) acc[i][j] = (floatx4){0.f, 0.f, 0.f, 0.f};

  const int srow = tid >> 3;                       // 0..31
  const int scolx = ((tid & 7) * 8) ^ ((srow & 7) * 8);  // swizzled source column
  const u16* Ag = A + (size_t)(m0 + srow) * K + scolx;
  const u16* Bg = Bm + (size_t)(n0 + srow) * K + scolx;

  for (int kt = 0; kt < K; kt += 64) {
    __syncthreads();
#pragma unroll
    for (int p = 0; p < 4; ++p) {
      load_lds16(Ag + (size_t)(p * 32) * K + kt, &As[p * 2048 + wave * 512]);
      load_lds16(Bg + (size_t)(p * 32) * K + kt, &Bs[p * 2048 + wave * 512]);
    }
    __syncthreads();

    short8 af[2][4], bfg[2][4];
#pragma unroll
    for (int ks = 0; ks < 2; ++ks) {
      const int kkx = (ks * 32 + quad * 8) ^ ((l15 & 7) * 8);
#pragma unroll
      for (int i = 0; i < 4; ++i) {
        af[ks][i]  = *(const short8*)&As[(wr * 64 + i * 16 + l15) * 64 + kkx];
        bfg[ks][i] = *(const short8*)&Bs[(wc * 64 + i * 16 + l15) * 64 + kkx];
      }
    }
#pragma unroll
    for (int ks = 0; ks < 2; ++ks)
#pragma unroll
      for (int mi = 0; mi < 4; ++mi)
#pragma unroll
        for (int ni = 0; ni < 4; ++ni)
          acc[mi][ni] = mfma16(af[ks][mi], bfg[ks][ni], acc[mi][ni]);
  }

  // Epilogue. C/D layout: col = lane&15, row = quad*4 + reg (m89-verified).
  if (blockIdx.z == 2) {
    // transposed V write: Vt[(b*16+h)*64 + d][t], 4 regs = t..t+3 contiguous
#pragma unroll
    for (int mi = 0; mi < 4; ++mi) {
#pragma unroll
      for (int ni = 0; ni < 4; ++ni) {
        const int row = m0 + wr * 64 + mi * 16 + quad * 4;   // token
        const int col = n0 + wc * 64 + ni * 16 + l15;        // channel
        const int b = row >> 11, t = row & 2047;
        const int h = col >> 6, d = col & 63;
        ushort4 pk;
        pk.x = f2bf(acc[mi][ni][0]); pk.y = f2bf(acc[mi][ni][1]);
        pk.z = f2bf(acc[mi][ni][2]); pk.w = f2bf(acc[mi][ni][3]);
        *(ushort4*)(VtOut + (((size_t)(b * 16 + h) * 64 + d) * SEQQ + t)) = pk;
      }
    }
    return;
  }
#pragma unroll
  for (int mi = 0; mi < 4; ++mi) {
#pragma unroll
    for (int ni = 0; ni < 4; ++ni) {
      const int row = m0 + wr * 64 + mi * 16 + quad * 4;
      const int col = n0 + wc * 64 + ni * 16 + l15;
      const float bv = bias ? bias[col] : 0.f;
#pragma unroll
      for (int r = 0; r < 4; ++r) {
        const float v = acc[mi][ni][r] * ascale + bv;
        if (f32out) ((float*)Cm)[(size_t)(row + r) * N + col] = v;
        else        ((u16*)Cm)[(size_t)(row + r) * N + col] = f2bf(v);
      }
    }
  }
}

// ---------------------------------------------------------------- flash attention
// ROUND-8: r7 8-wave + permlane structure, with KVBLK 64 -> 128.
// RATIONALE: r6 (Ps-LDS, 2.16M conflicts, 64KB) and r7 (permlane, 0 conflicts,
// 32KB) both measure 80 us with every pipe <31% busy -> the limiter is the
// per-iteration serial skeleton (barrier + staging drain + dependent chain),
// paid 50x/CU. This round halves that count: stage 128-key tiles, run the
// proven 64-key compute body twice per tile (sub-iterations, u = 2t+sub).
// Masking formula is position-generic, so only staging geometry + index
// mapping change. LDS 64KB (Ks 2x[128][64] + Vs 2x[64][128]) -> still 2
// blocks/CU. Per-CU: (16-g)+(9+g) = 25 iters, constant (balance preserved).
// V's 256B rows use per-64-col-half XOR-8 swizzle (write-side pre-swizzled
// global source, read-side same XOR -> rule-21 both-sides consistency; max
// 2-way bank aliasing, free per m136). Plus T5 setprio(1) around the 4 MFMA
// clusters (catalog m191: +4-7% attn when waves have role diversity).
__device__ __forceinline__ short8 mk8(uint32_t a, uint32_t b, uint32_t c, uint32_t d) {
  union { uint32_t u[4]; short8 s; } t;
  t.u[0] = a; t.u[1] = b; t.u[2] = c; t.u[3] = d;
  return t.s;
}

// exp2 + pack one side's S^T tiles -> denominator + 8 bf16x2 words (in regs)
__device__ __forceinline__ void softmax_reg(
    const floatx4 (&st)[4], float& lp, uint32_t (&w)[4][2]) {
#pragma unroll
  for (int ni = 0; ni < 4; ++ni) {
    const float p0 = __builtin_amdgcn_exp2f(st[ni][0]);
    const float p1 = __builtin_amdgcn_exp2f(st[ni][1]);
    const float p2 = __builtin_amdgcn_exp2f(st[ni][2]);
    const float p3 = __builtin_amdgcn_exp2f(st[ni][3]);
    lp += (p0 + p1) + (p2 + p3);
    // w[ni][0] = keys(ni*16+quad*4 +0,+1), w[ni][1] = (+2,+3), packed bf16x2
    w[ni][0] = __builtin_amdgcn_perm(__float_as_uint(p1), __float_as_uint(p0), 0x07060302u);
    w[ni][1] = __builtin_amdgcn_perm(__float_as_uint(p3), __float_as_uint(p2), 0x07060302u);
  }
}

// build PV A-operand (keys kc*32+quad*8+{0..7} at q=l15) from the 4 quads'
// packed tiles via the quad-transpose swap network (r2-derived, r3/r4-proven):
__device__ __forceinline__ short8 pf_prep(const uint32_t (&w)[4][2], int kc) {
  uint32_t y0 = w[2 * kc][0], z0 = w[2 * kc + 1][0];
  asm("v_permlane32_swap_b32 %0, %1" : "+v"(y0), "+v"(z0));
  asm("v_permlane16_swap_b32 %0, %1" : "+v"(y0), "+v"(z0));
  uint32_t y1 = w[2 * kc][1], z1 = w[2 * kc + 1][1];
  asm("v_permlane32_swap_b32 %0, %1" : "+v"(y1), "+v"(z1));
  asm("v_permlane16_swap_b32 %0, %1" : "+v"(y1), "+v"(z1));
  return mk8(y0, y1, z0, z1);
}

__global__ __launch_bounds__(512) void k_attn(
    const u16* __restrict__ Q, const u16* __restrict__ Kg,
    const u16* __restrict__ Vt, u16* __restrict__ O) {
  __shared__ __align__(16) u16 Ks[2][128 * 64];   // [key 0..127][d 0..63]
  __shared__ __align__(16) u16 Vs[2][64 * 128];   // [d 0..63][key 0..127]
  const int tid = threadIdx.x, lane = tid & 63, wave = tid >> 6;
  const int quad = lane >> 4, l15 = lane & 15;

  // balanced (g, bh): CU c hosts blocks c and c+256 -> g and 7-g
  // -> per-CU loop total (16-g)+(9+g) = 25, constant.
  const int lin = blockIdx.x;
  const int c = lin & 255, k2 = lin >> 8;
  const int g = k2 ? (7 - (c & 7)) : (c & 7);       // pair-group 0..7
  const int bh = (c >> 3) | (k2 << 5);              // 0..63
  const int b = bh >> 4, h = bh & 15;

  const int wgrp = wave >> 2, wsub = wave & 3;
  const int a = 2 * g + wgrp;                // this wave's pair index 0..15
  const int qwA = 64 * a + wsub * 16;
  const int qwB = SEQQ - 64 * (a + 1) + wsub * 16;
  const int nT = 16 - g;                     // 128-wide tiles in block loop
  const int uB = 31 - a;                     // B diag position (64-key units)

  const u16* kbase = Kg + (size_t)(b * SEQQ) * D_MODEL + h * HDIM;
  const u16* vbase = Vt + (size_t)bh * (HDIM * SEQQ);

  // K staging source: per call, rows(key) 0..63 of 128B; wave w -> rows 8w..8w+7
  const int krow = tid >> 3;                            // 0..63
  const int kcol = ((tid & 7) * 8) ^ ((krow & 7) * 8);  // 8 slots of 16B, XOR-8
  // V staging source: per call, rows(d) 0..31 of 256B; 16 slots of 16B per row,
  // XOR-8 within each 64-col half (slot>>3 = half), matching the read swizzle.
  const int vrow = tid >> 4;                            // 0..31
  const int vslot = tid & 15;
  const int vcol = (vslot >> 3) * 64 + (((vslot & 7) ^ (vrow & 7)) * 8);

#define STAGE_KV(tt, buf)                                                           \
  {                                                                                 \
    const int kt_ = (tt) * 128;                                                     \
    load_lds16(kbase + (size_t)(kt_ + krow) * D_MODEL + kcol,                       \
               &Ks[buf][wave * 512]);                                               \
    load_lds16(kbase + (size_t)(kt_ + 64 + krow) * D_MODEL + kcol,                  \
               &Ks[buf][4096 + wave * 512]);                                        \
    load_lds16(vbase + (size_t)vrow * SEQQ + kt_ + vcol,                            \
               &Vs[buf][wave * 512]);                                               \
    load_lds16(vbase + (size_t)(32 + vrow) * SEQQ + kt_ + vcol,                     \
               &Vs[buf][4096 + wave * 512]);                                        \
  }

  // issue first staging before anything else
  STAGE_KV(0, 0);

  // Q fragments ([idx=l15][k=quad*8+j]); Q pre-scaled by 1/sqrt(hd)*log2e.
  short8 qfA[2], qfB[2];
  {
    const u16* qa = Q + (size_t)(b * SEQQ + qwA + l15) * D_MODEL + h * HDIM;
    const u16* qb = Q + (size_t)(b * SEQQ + qwB + l15) * D_MODEL + h * HDIM;
#pragma unroll
    for (int ks = 0; ks < 2; ++ks) {
      qfA[ks] = *(const short8*)(qa + ks * 32 + quad * 8);
      qfB[ks] = *(const short8*)(qb + ks * 32 + quad * 8);
    }
  }

  floatx4 accA[4], accB[4];
  float lAp = 0.f, lBp = 0.f;     // per-lane partial softmax denominators
#pragma unroll
  for (int i = 0; i < 4; ++i) {
    accA[i] = (floatx4){0.f, 0.f, 0.f, 0.f};
    accB[i] = (floatx4){0.f, 0.f, 0.f, 0.f};
  }

  for (int t = 0; t < nT; ++t) {
    const int cur = t & 1;
    __syncthreads();   // drains stage(t) (vmcnt) + all reads of buf[cur^1]
    if (t + 1 < nT) STAGE_KV(t + 1, cur ^ 1);   // prefetch next 128-key tile

#pragma unroll
    for (int sub = 0; sub < 2; ++sub) {
      const int u = 2 * t + sub;       // 64-key tile index
      const bool doA = (u <= a);       // wave-uniform
      const bool doB = (u <= uB);      // wave-uniform

      // K fragments ([key=l15][d=quad*8+j])
      short8 kf[4][2];
#pragma unroll
      for (int ni = 0; ni < 4; ++ni)
#pragma unroll
        for (int ks = 0; ks < 2; ++ks)
          kf[ni][ks] = *(const short8*)&Ks[cur][(sub * 64 + ni * 16 + l15) * 64 +
                                               ((ks * 32 + quad * 8) ^ ((l15 & 7) * 8))];
      // V fragments ([d=l15][key=quad*8+j]); row stride 128, per-half swizzle
      short8 vf[2][4];
#pragma unroll
      for (int kc = 0; kc < 2; ++kc)
#pragma unroll
        for (int di = 0; di < 4; ++di)
          vf[kc][di] = *(const short8*)&Vs[cur][(di * 16 + l15) * 128 + sub * 64 +
                                               ((kc * 32 + quad * 8) ^ ((l15 & 7) * 8))];

      uint32_t wA[4][2], wB[4][2];
      if (doA) {
        floatx4 st[4];   // S^T: row=key (quad*4+r, tile ni), col=q (l15)
        __builtin_amdgcn_s_setprio(1);
#pragma unroll
        for (int ni = 0; ni < 4; ++ni) {
          floatx4 s = (floatx4){0.f, 0.f, 0.f, 0.f};
          s = mfma16(kf[ni][0], qfA[0], s);
          s = mfma16(kf[ni][1], qfA[1], s);
          st[ni] = s;
        }
        __builtin_amdgcn_s_setprio(0);
        if (u == a) {   // diagonal tile of A: mask key > q
          const int qg = qwA + l15;
#pragma unroll
          for (int ni = 0; ni < 4; ++ni) {
            const int kg = u * 64 + ni * 16 + quad * 4;
#pragma unroll
            for (int r = 0; r < 4; ++r)
              if (kg + r > qg) st[ni][r] = -1e30f;
          }
        }
        softmax_reg(st, lAp, wA);
      }
      if (doB) {
        floatx4 st[4];
        __builtin_amdgcn_s_setprio(1);
#pragma unroll
        for (int ni = 0; ni < 4; ++ni) {
          floatx4 s = (floatx4){0.f, 0.f, 0.f, 0.f};
          s = mfma16(kf[ni][0], qfB[0], s);
          s = mfma16(kf[ni][1], qfB[1], s);
          st[ni] = s;
        }
        __builtin_amdgcn_s_setprio(0);
        if (u == uB) {   // diagonal tile of B
          const int qg = qwB + l15;
#pragma unroll
          for (int ni = 0; ni < 4; ++ni) {
            const int kg = u * 64 + ni * 16 + quad * 4;
#pragma unroll
            for (int r = 0; r < 4; ++r)
              if (kg + r > qg) st[ni][r] = -1e30f;
          }
        }
        softmax_reg(st, lBp, wB);
      }
      // PV: pf built in-register (permlane quad-transpose); vf shared by A/B
#pragma unroll
      for (int kc = 0; kc < 2; ++kc) {
        if (doA) {
          const short8 pfA = pf_prep(wA, kc);
          __builtin_amdgcn_s_setprio(1);
#pragma unroll
          for (int di = 0; di < 4; ++di)
            accA[di] = mfma16(pfA, vf[kc][di], accA[di]);
          __builtin_amdgcn_s_setprio(0);
        }
        if (doB) {
          const short8 pfB = pf_prep(wB, kc);
          __builtin_amdgcn_s_setprio(1);
#pragma unroll
          for (int di = 0; di < 4; ++di)
            accB[di] = mfma16(pfB, vf[kc][di], accB[di]);
          __builtin_amdgcn_s_setprio(0);
        }
      }
    }
  }

  // l reduce: across the 4 quad groups (same l15) -> every lane holds l(q=l15)
  lAp += __shfl_xor(lAp, 16); lAp += __shfl_xor(lAp, 32);
  lBp += __shfl_xor(lBp, 16); lBp += __shfl_xor(lBp, 32);

  // epilogue: O rows q=quad*4+r, cols d=di*16+l15; l for row via shfl
  {
    u16* orow = O + (size_t)(b * SEQQ + qwA + quad * 4) * D_MODEL + h * HDIM + l15;
#pragma unroll
    for (int r = 0; r < 4; ++r) {
      const float inv = 1.0f / __shfl(lAp, quad * 4 + r, 16);
#pragma unroll
      for (int di = 0; di < 4; ++di)
        orow[(size_t)r * D_MODEL + di * 16] = f2bf(accA[di][r] * inv);
    }
  }
  {
    u16* orow = O + (size_t)(b * SEQQ + qwB + quad * 4) * D_MODEL + h * HDIM + l15;
#pragma unroll
    for (int r = 0; r < 4; ++r) {
      const float inv = 1.0f / __shfl(lBp, quad * 4 + r, 16);
#pragma unroll
      for (int di = 0; di < 4; ++di)
        orow[(size_t)r * D_MODEL + di * 16] = f2bf(accB[di][r] * inv);
    }
  }
}

// ---------------------------------------------------------------- launch
extern "C" void kernel_launch(void* const* d_in, const int* in_sizes, int n_in,
                              void* d_out, int out_size, void* d_ws, size_t ws_size,
                              hipStream_t stream) {
  const float* X  = (const float*)d_in[0];
  const float* Wq = (const float*)d_in[1];
  const float* Wk = (const float*)d_in[2];
  const float* Wv = (const float*)d_in[3];
  const float* Wo = (const float*)d_in[4];
  const float* bo = (const float*)d_in[5];
  float* out = (float*)d_out;

  u16* ws = (u16*)d_ws;
  const size_t NE = (size_t)MTOT * D_MODEL;    // 8,388,608
  u16* Xb  = ws;
  u16* Qb  = Xb + NE;
  u16* Kb  = Qb + NE;
  u16* Vt  = Kb + NE;          // V projection written directly transposed
  u16* Cb  = Vt + NE;
  u16* Wqb = Cb + NE;
  u16* Wkb = Wqb + (size_t)D_MODEL * D_MODEL;
  u16* Wvb = Wkb + (size_t)D_MODEL * D_MODEL;
  u16* Wob = Wvb + (size_t)D_MODEL * D_MODEL;

  const float SCL2E = 0.18033688f;   // (1/sqrt(64)) * log2(e), folded into Q

  // 1. all casts in one launch
  k_cast_all<<<12288, 256, 0, stream>>>(X, Wq, Wk, Wv, Wo, Xb, Wqb, Wkb, Wvb, Wob);

  // 2. fused QKV projections (Q pre-scaled; V written transposed into Vt)
  k_gemm_bt<<<dim3(D_MODEL / 128, MTOT / 128, 3), 256, 0, stream>>>(
      Xb, Wqb, Wkb, Wvb, Qb, Kb, Vt, nullptr, MTOT, D_MODEL, D_MODEL, 0, SCL2E);

  // 3. causal flash attention, 8-wave blocks, KVBLK=128, balanced 1D grid
  k_attn<<<512, 512, 0, stream>>>(Qb, Kb, Vt, Cb);

  // 4. output projection + bias, f32 out
  k_gemm_bt<<<dim3(D_MODEL / 128, MTOT / 128, 1), 256, 0, stream>>>(
      Cb, Wob, Wob, Wob, out, out, nullptr, bo, MTOT, D_MODEL, D_MODEL, 1, 1.0f);
}

// Round 9
// 248.275 us; speedup vs baseline: 1.1061x; 1.0932x over previous
//
#include <hip/hip_runtime.h>
#include <cstdint>
#include <cstddef>

// Problem constants (MultiHeadAttention: B=4, T=2048, d_model=1024, H=16, hd=64)
#define D_MODEL 1024
#define SEQQ    2048
#define NBATCH  4
#define NHEAD   16
#define HDIM    64
#define MTOT    (NBATCH * SEQQ)   // 8192 rows

typedef __attribute__((ext_vector_type(8))) short short8;   // 8 x bf16 (4 VGPRs) — MFMA A/B frag
typedef __attribute__((ext_vector_type(4))) float floatx4;  // MFMA C/D frag
typedef unsigned short u16;                                  // bf16 bits

__device__ __forceinline__ u16 f2bf(float f) {
  union { float f; uint32_t u; } a; a.f = f;
  uint32_t u = a.u;
  u += 0x7fffu + ((u >> 16) & 1u);   // RN-even
  return (u16)(u >> 16);
}

__device__ __forceinline__ floatx4 mfma16(short8 a, short8 b, floatx4 c) {
  return __builtin_amdgcn_mfma_f32_16x16x32_bf16(a, b, c, 0, 0, 0);
}

// async global->LDS, 16B per lane. LDS dest = wave-uniform base + lane*16.
__device__ __forceinline__ void load_lds16(const void* g, void* l) {
  __builtin_amdgcn_global_load_lds(
      (const __attribute__((address_space(1))) uint32_t*)g,
      (__attribute__((address_space(3))) uint32_t*)l, 16, 0, 0);
}

// ---------------------------------------------------------------- fused casts f32->bf16
// blocks [0, 8192): X. blocks [8192, 12288): weights, 1024 blocks each.
__global__ __launch_bounds__(256) void k_cast_all(
    const float* __restrict__ X, const float* __restrict__ w0,
    const float* __restrict__ w1, const float* __restrict__ w2,
    const float* __restrict__ w3,
    u16* __restrict__ xb, u16* __restrict__ y0, u16* __restrict__ y1,
    u16* __restrict__ y2, u16* __restrict__ y3) {
  const int bx = blockIdx.x;
  const float* src; u16* dst; int i;
  if (bx < 8192) {
    src = X; dst = xb; i = (bx * 256 + threadIdx.x) * 4;
  } else {
    const int w = (bx - 8192) >> 10;
    src = (w == 0) ? w0 : (w == 1) ? w1 : (w == 2) ? w2 : w3;
    dst = (w == 0) ? y0 : (w == 1) ? y1 : (w == 2) ? y2 : y3;
    i = (((bx - 8192) & 1023) * 256 + threadIdx.x) * 4;
  }
  float4 v = *(const float4*)(src + i);
  ushort4 o;
  o.x = f2bf(v.x); o.y = f2bf(v.y); o.z = f2bf(v.z); o.w = f2bf(v.w);
  *(ushort4*)(dst + i) = o;
}

// ---------------------------------------------------------------- GEMM  C = A @ B^T (+bias)
// ROUND-9: two changes vs the r8 GEMM (attn untouched this round):
// 1. PIPELINED K-LOOP (attn-proven pattern): double-buffered LDS, ONE
//    barrier-then-stage order so stage(t+1) overlaps compute(t). Old loop
//    (barrier; stage; barrier; compute) exposed full global->LDS latency
//    per K-step. __syncthreads drain semantics give exactly the needed
//    wait: stage(t+1) is drained at barrier(t+1), after compute(t) covered
//    its latency. Identical sync structure to k_attn (r0-r8 proven).
// 2. XCD/L2 REMAP (T1): 1-D grid, swz=(bx&7)*64+(bx>>3); HW round-robins
//    linear id over 8 XCDs -> XCD k owns swz in [64k, 64k+64) = 8 contiguous
//    M-panels x all 8 N-tiles. Working set 8x256KB A + 2MB B = ~4MB = one
//    XCD L2. Old grid scattered A-panel sharers over all 8 L2s (FETCH 175MB
//    vs ~100MB ideal).
// ascaleQ: extra scale on the z==0 output (folds 1/sqrt(hd)*log2e into Q).
// z==2 (V projection): epilogue writes TRANSPOSED into Vt [bh][64][2048].
__global__ __launch_bounds__(256) void k_gemm_bt(
    const u16* __restrict__ A,
    const u16* __restrict__ B0, const u16* __restrict__ B1, const u16* __restrict__ B2,
    void* __restrict__ C0, void* __restrict__ C1, u16* __restrict__ VtOut,
    const float* __restrict__ bias, int M, int N, int K, int f32out, float ascaleQ) {
  __shared__ __align__(16) u16 As[2][128 * 64];
  __shared__ __align__(16) u16 Bs[2][128 * 64];
  const int tid = threadIdx.x;
  const int lane = tid & 63, wave = tid >> 6;
  const int quad = lane >> 4, l15 = lane & 15;

  // XCD/L2-aware remap (see header). 512 blocks per z.
  const int bx = blockIdx.x;
  const int swz = (bx & 7) * 64 + (bx >> 3);
  const int m0 = (swz >> 3) * 128, n0 = (swz & 7) * 128;

  const int wr = wave >> 1, wc = wave & 1;
  const u16* Bm = (blockIdx.z == 0) ? B0 : (blockIdx.z == 1 ? B1 : B2);
  void* Cm = (blockIdx.z == 0) ? C0 : C1;
  const float ascale = (blockIdx.z == 0) ? ascaleQ : 1.0f;

  floatx4 acc[4][4];
#pragma unroll
  for (int i = 0; i < 4; ++i)
#pragma unroll
    for (int j = 0; j < 4; ++j) acc[i][j] = (floatx4){0.f, 0.f, 0.f, 0.f};

  const int srow = tid >> 3;                       // 0..31
  const int scolx = ((tid & 7) * 8) ^ ((srow & 7) * 8);  // swizzled source column
  const u16* Ag = A + (size_t)(m0 + srow) * K + scolx;
  const u16* Bg = Bm + (size_t)(n0 + srow) * K + scolx;

#define STAGE_AB(tt, buf)                                                            \
  {                                                                                  \
    const int kk_ = (tt) * 64;                                                       \
    _Pragma("unroll")                                                                \
    for (int p = 0; p < 4; ++p) {                                                    \
      load_lds16(Ag + (size_t)(p * 32) * K + kk_, &As[buf][p * 2048 + wave * 512]);  \
      load_lds16(Bg + (size_t)(p * 32) * K + kk_, &Bs[buf][p * 2048 + wave * 512]);  \
    }                                                                                \
  }

  const int nIt = K / 64;   // 16
  STAGE_AB(0, 0);           // prologue: first tile in flight

  for (int it = 0; it < nIt; ++it) {
    const int cur = it & 1;
    __syncthreads();                      // drains stage(it); prior reads of buf[cur^1] done
    if (it + 1 < nIt) STAGE_AB(it + 1, cur ^ 1);   // overlaps compute(it)

    short8 af[2][4], bfg[2][4];
#pragma unroll
    for (int ks = 0; ks < 2; ++ks) {
      const int kkx = (ks * 32 + quad * 8) ^ ((l15 & 7) * 8);
#pragma unroll
      for (int i = 0; i < 4; ++i) {
        af[ks][i]  = *(const short8*)&As[cur][(wr * 64 + i * 16 + l15) * 64 + kkx];
        bfg[ks][i] = *(const short8*)&Bs[cur][(wc * 64 + i * 16 + l15) * 64 + kkx];
      }
    }
#pragma unroll
    for (int ks = 0; ks < 2; ++ks)
#pragma unroll
      for (int mi = 0; mi < 4; ++mi)
#pragma unroll
        for (int ni = 0; ni < 4; ++ni)
          acc[mi][ni] = mfma16(af[ks][mi], bfg[ks][ni], acc[mi][ni]);
  }
#undef STAGE_AB

  // Epilogue. C/D layout: col = lane&15, row = quad*4 + reg (m89-verified).
  if (blockIdx.z == 2) {
    // transposed V write: Vt[(b*16+h)*64 + d][t], 4 regs = t..t+3 contiguous
#pragma unroll
    for (int mi = 0; mi < 4; ++mi) {
#pragma unroll
      for (int ni = 0; ni < 4; ++ni) {
        const int row = m0 + wr * 64 + mi * 16 + quad * 4;   // token
        const int col = n0 + wc * 64 + ni * 16 + l15;        // channel
        const int b = row >> 11, t = row & 2047;
        const int h = col >> 6, d = col & 63;
        ushort4 pk;
        pk.x = f2bf(acc[mi][ni][0]); pk.y = f2bf(acc[mi][ni][1]);
        pk.z = f2bf(acc[mi][ni][2]); pk.w = f2bf(acc[mi][ni][3]);
        *(ushort4*)(VtOut + (((size_t)(b * 16 + h) * 64 + d) * SEQQ + t)) = pk;
      }
    }
    return;
  }
#pragma unroll
  for (int mi = 0; mi < 4; ++mi) {
#pragma unroll
    for (int ni = 0; ni < 4; ++ni) {
      const int row = m0 + wr * 64 + mi * 16 + quad * 4;
      const int col = n0 + wc * 64 + ni * 16 + l15;
      const float bv = bias ? bias[col] : 0.f;
#pragma unroll
      for (int r = 0; r < 4; ++r) {
        const float v = acc[mi][ni][r] * ascale + bv;
        if (f32out) ((float*)Cm)[(size_t)(row + r) * N + col] = v;
        else        ((u16*)Cm)[(size_t)(row + r) * N + col] = f2bf(v);
      }
    }
  }
}

// ---------------------------------------------------------------- flash attention
// r8 structure (KVBLK=128, 8-wave blocks, permlane P-transpose, setprio) —
// measured: dropped below the GEMMs (<74us). Untouched this round.
__device__ __forceinline__ short8 mk8(uint32_t a, uint32_t b, uint32_t c, uint32_t d) {
  union { uint32_t u[4]; short8 s; } t;
  t.u[0] = a; t.u[1] = b; t.u[2] = c; t.u[3] = d;
  return t.s;
}

// exp2 + pack one side's S^T tiles -> denominator + 8 bf16x2 words (in regs)
__device__ __forceinline__ void softmax_reg(
    const floatx4 (&st)[4], float& lp, uint32_t (&w)[4][2]) {
#pragma unroll
  for (int ni = 0; ni < 4; ++ni) {
    const float p0 = __builtin_amdgcn_exp2f(st[ni][0]);
    const float p1 = __builtin_amdgcn_exp2f(st[ni][1]);
    const float p2 = __builtin_amdgcn_exp2f(st[ni][2]);
    const float p3 = __builtin_amdgcn_exp2f(st[ni][3]);
    lp += (p0 + p1) + (p2 + p3);
    // w[ni][0] = keys(ni*16+quad*4 +0,+1), w[ni][1] = (+2,+3), packed bf16x2
    w[ni][0] = __builtin_amdgcn_perm(__float_as_uint(p1), __float_as_uint(p0), 0x07060302u);
    w[ni][1] = __builtin_amdgcn_perm(__float_as_uint(p3), __float_as_uint(p2), 0x07060302u);
  }
}

// build PV A-operand (keys kc*32+quad*8+{0..7} at q=l15) from the 4 quads'
// packed tiles via the quad-transpose swap network (r2-derived, r3/r4-proven):
__device__ __forceinline__ short8 pf_prep(const uint32_t (&w)[4][2], int kc) {
  uint32_t y0 = w[2 * kc][0], z0 = w[2 * kc + 1][0];
  asm("v_permlane32_swap_b32 %0, %1" : "+v"(y0), "+v"(z0));
  asm("v_permlane16_swap_b32 %0, %1" : "+v"(y0), "+v"(z0));
  uint32_t y1 = w[2 * kc][1], z1 = w[2 * kc + 1][1];
  asm("v_permlane32_swap_b32 %0, %1" : "+v"(y1), "+v"(z1));
  asm("v_permlane16_swap_b32 %0, %1" : "+v"(y1), "+v"(z1));
  return mk8(y0, y1, z0, z1);
}

__global__ __launch_bounds__(512) void k_attn(
    const u16* __restrict__ Q, const u16* __restrict__ Kg,
    const u16* __restrict__ Vt, u16* __restrict__ O) {
  __shared__ __align__(16) u16 Ks[2][128 * 64];   // [key 0..127][d 0..63]
  __shared__ __align__(16) u16 Vs[2][64 * 128];   // [d 0..63][key 0..127]
  const int tid = threadIdx.x, lane = tid & 63, wave = tid >> 6;
  const int quad = lane >> 4, l15 = lane & 15;

  // balanced (g, bh): CU c hosts blocks c and c+256 -> g and 7-g
  // -> per-CU loop total (16-g)+(9+g) = 25, constant.
  const int lin = blockIdx.x;
  const int c = lin & 255, k2 = lin >> 8;
  const int g = k2 ? (7 - (c & 7)) : (c & 7);       // pair-group 0..7
  const int bh = (c >> 3) | (k2 << 5);              // 0..63
  const int b = bh >> 4, h = bh & 15;

  const int wgrp = wave >> 2, wsub = wave & 3;
  const int a = 2 * g + wgrp;                // this wave's pair index 0..15
  const int qwA = 64 * a + wsub * 16;
  const int qwB = SEQQ - 64 * (a + 1) + wsub * 16;
  const int nT = 16 - g;                     // 128-wide tiles in block loop
  const int uB = 31 - a;                     // B diag position (64-key units)

  const u16* kbase = Kg + (size_t)(b * SEQQ) * D_MODEL + h * HDIM;
  const u16* vbase = Vt + (size_t)bh * (HDIM * SEQQ);

  // K staging source: per call, rows(key) 0..63 of 128B; wave w -> rows 8w..8w+7
  const int krow = tid >> 3;                            // 0..63
  const int kcol = ((tid & 7) * 8) ^ ((krow & 7) * 8);  // 8 slots of 16B, XOR-8
  // V staging source: per call, rows(d) 0..31 of 256B; 16 slots of 16B per row,
  // XOR-8 within each 64-col half (slot>>3 = half), matching the read swizzle.
  const int vrow = tid >> 4;                            // 0..31
  const int vslot = tid & 15;
  const int vcol = (vslot >> 3) * 64 + (((vslot & 7) ^ (vrow & 7)) * 8);

#define STAGE_KV(tt, buf)                                                           \
  {                                                                                 \
    const int kt_ = (tt) * 128;                                                     \
    load_lds16(kbase + (size_t)(kt_ + krow) * D_MODEL + kcol,                       \
               &Ks[buf][wave * 512]);                                               \
    load_lds16(kbase + (size_t)(kt_ + 64 + krow) * D_MODEL + kcol,                  \
               &Ks[buf][4096 + wave * 512]);                                        \
    load_lds16(vbase + (size_t)vrow * SEQQ + kt_ + vcol,                            \
               &Vs[buf][wave * 512]);                                               \
    load_lds16(vbase + (size_t)(32 + vrow) * SEQQ + kt_ + vcol,                     \
               &Vs[buf][4096 + wave * 512]);                                        \
  }

  // issue first staging before anything else
  STAGE_KV(0, 0);

  // Q fragments ([idx=l15][k=quad*8+j]); Q pre-scaled by 1/sqrt(hd)*log2e.
  short8 qfA[2], qfB[2];
  {
    const u16* qa = Q + (size_t)(b * SEQQ + qwA + l15) * D_MODEL + h * HDIM;
    const u16* qb = Q + (size_t)(b * SEQQ + qwB + l15) * D_MODEL + h * HDIM;
#pragma unroll
    for (int ks = 0; ks < 2; ++ks) {
      qfA[ks] = *(const short8*)(qa + ks * 32 + quad * 8);
      qfB[ks] = *(const short8*)(qb + ks * 32 + quad * 8);
    }
  }

  floatx4 accA[4], accB[4];
  float lAp = 0.f, lBp = 0.f;     // per-lane partial softmax denominators
#pragma unroll
  for (int i = 0; i < 4; ++i) {
    accA[i] = (floatx4){0.f, 0.f, 0.f, 0.f};
    accB[i] = (floatx4){0.f, 0.f, 0.f, 0.f};
  }

  for (int t = 0; t < nT; ++t) {
    const int cur = t & 1;
    __syncthreads();   // drains stage(t) (vmcnt) + all reads of buf[cur^1]
    if (t + 1 < nT) STAGE_KV(t + 1, cur ^ 1);   // prefetch next 128-key tile

#pragma unroll
    for (int sub = 0; sub < 2; ++sub) {
      const int u = 2 * t + sub;       // 64-key tile index
      const bool doA = (u <= a);       // wave-uniform
      const bool doB = (u <= uB);      // wave-uniform

      // K fragments ([key=l15][d=quad*8+j])
      short8 kf[4][2];
#pragma unroll
      for (int ni = 0; ni < 4; ++ni)
#pragma unroll
        for (int ks = 0; ks < 2; ++ks)
          kf[ni][ks] = *(const short8*)&Ks[cur][(sub * 64 + ni * 16 + l15) * 64 +
                                               ((ks * 32 + quad * 8) ^ ((l15 & 7) * 8))];
      // V fragments ([d=l15][key=quad*8+j]); row stride 128, per-half swizzle
      short8 vf[2][4];
#pragma unroll
      for (int kc = 0; kc < 2; ++kc)
#pragma unroll
        for (int di = 0; di < 4; ++di)
          vf[kc][di] = *(const short8*)&Vs[cur][(di * 16 + l15) * 128 + sub * 64 +
                                               ((kc * 32 + quad * 8) ^ ((l15 & 7) * 8))];

      uint32_t wA[4][2], wB[4][2];
      if (doA) {
        floatx4 st[4];   // S^T: row=key (quad*4+r, tile ni), col=q (l15)
        __builtin_amdgcn_s_setprio(1);
#pragma unroll
        for (int ni = 0; ni < 4; ++ni) {
          floatx4 s = (floatx4){0.f, 0.f, 0.f, 0.f};
          s = mfma16(kf[ni][0], qfA[0], s);
          s = mfma16(kf[ni][1], qfA[1], s);
          st[ni] = s;
        }
        __builtin_amdgcn_s_setprio(0);
        if (u == a) {   // diagonal tile of A: mask key > q
          const int qg = qwA + l15;
#pragma unroll
          for (int ni = 0; ni < 4; ++ni) {
            const int kg = u * 64 + ni * 16 + quad * 4;
#pragma unroll
            for (int r = 0; r < 4; ++r)
              if (kg + r > qg) st[ni][r] = -1e30f;
          }
        }
        softmax_reg(st, lAp, wA);
      }
      if (doB) {
        floatx4 st[4];
        __builtin_amdgcn_s_setprio(1);
#pragma unroll
        for (int ni = 0; ni < 4; ++ni) {
          floatx4 s = (floatx4){0.f, 0.f, 0.f, 0.f};
          s = mfma16(kf[ni][0], qfB[0], s);
          s = mfma16(kf[ni][1], qfB[1], s);
          st[ni] = s;
        }
        __builtin_amdgcn_s_setprio(0);
        if (u == uB) {   // diagonal tile of B
          const int qg = qwB + l15;
#pragma unroll
          for (int ni = 0; ni < 4; ++ni) {
            const int kg = u * 64 + ni * 16 + quad * 4;
#pragma unroll
            for (int r = 0; r < 4; ++r)
              if (kg + r > qg) st[ni][r] = -1e30f;
          }
        }
        softmax_reg(st, lBp, wB);
      }
      // PV: pf built in-register (permlane quad-transpose); vf shared by A/B
#pragma unroll
      for (int kc = 0; kc < 2; ++kc) {
        if (doA) {
          const short8 pfA = pf_prep(wA, kc);
          __builtin_amdgcn_s_setprio(1);
#pragma unroll
          for (int di = 0; di < 4; ++di)
            accA[di] = mfma16(pfA, vf[kc][di], accA[di]);
          __builtin_amdgcn_s_setprio(0);
        }
        if (doB) {
          const short8 pfB = pf_prep(wB, kc);
          __builtin_amdgcn_s_setprio(1);
#pragma unroll
          for (int di = 0; di < 4; ++di)
            accB[di] = mfma16(pfB, vf[kc][di], accB[di]);
          __builtin_amdgcn_s_setprio(0);
        }
      }
    }
  }

  // l reduce: across the 4 quad groups (same l15) -> every lane holds l(q=l15)
  lAp += __shfl_xor(lAp, 16); lAp += __shfl_xor(lAp, 32);
  lBp += __shfl_xor(lBp, 16); lBp += __shfl_xor(lBp, 32);

  // epilogue: O rows q=quad*4+r, cols d=di*16+l15; l for row via shfl
  {
    u16* orow = O + (size_t)(b * SEQQ + qwA + quad * 4) * D_MODEL + h * HDIM + l15;
#pragma unroll
    for (int r = 0; r < 4; ++r) {
      const float inv = 1.0f / __shfl(lAp, quad * 4 + r, 16);
#pragma unroll
      for (int di = 0; di < 4; ++di)
        orow[(size_t)r * D_MODEL + di * 16] = f2bf(accA[di][r] * inv);
    }
  }
  {
    u16* orow = O + (size_t)(b * SEQQ + qwB + quad * 4) * D_MODEL + h * HDIM + l15;
#pragma unroll
    for (int r = 0; r < 4; ++r) {
      const float inv = 1.0f / __shfl(lBp, quad * 4 + r, 16);
#pragma unroll
      for (int di = 0; di < 4; ++di)
        orow[(size_t)r * D_MODEL + di * 16] = f2bf(accB[di][r] * inv);
    }
  }
}

// ---------------------------------------------------------------- launch
extern "C" void kernel_launch(void* const* d_in, const int* in_sizes, int n_in,
                              void* d_out, int out_size, void* d_ws, size_t ws_size,
                              hipStream_t stream) {
  const float* X  = (const float*)d_in[0];
  const float* Wq = (const float*)d_in[1];
  const float* Wk = (const float*)d_in[2];
  const float* Wv = (const float*)d_in[3];
  const float* Wo = (const float*)d_in[4];
  const float* bo = (const float*)d_in[5];
  float* out = (float*)d_out;

  u16* ws = (u16*)d_ws;
  const size_t NE = (size_t)MTOT * D_MODEL;    // 8,388,608
  u16* Xb  = ws;
  u16* Qb  = Xb + NE;
  u16* Kb  = Qb + NE;
  u16* Vt  = Kb + NE;          // V projection written directly transposed
  u16* Cb  = Vt + NE;
  u16* Wqb = Cb + NE;
  u16* Wkb = Wqb + (size_t)D_MODEL * D_MODEL;
  u16* Wvb = Wkb + (size_t)D_MODEL * D_MODEL;
  u16* Wob = Wvb + (size_t)D_MODEL * D_MODEL;

  const float SCL2E = 0.18033688f;   // (1/sqrt(64)) * log2(e), folded into Q

  // 1. all casts in one launch
  k_cast_all<<<12288, 256, 0, stream>>>(X, Wq, Wk, Wv, Wo, Xb, Wqb, Wkb, Wvb, Wob);

  // 2. fused QKV projections (Q pre-scaled; V written transposed into Vt)
  //    1-D grid of 512 per z, XCD/L2-remapped inside the kernel.
  k_gemm_bt<<<dim3(512, 1, 3), 256, 0, stream>>>(
      Xb, Wqb, Wkb, Wvb, Qb, Kb, Vt, nullptr, MTOT, D_MODEL, D_MODEL, 0, SCL2E);

  // 3. causal flash attention, 8-wave blocks, KVBLK=128, balanced 1D grid
  k_attn<<<512, 512, 0, stream>>>(Qb, Kb, Vt, Cb);

  // 4. output projection + bias, f32 out
  k_gemm_bt<<<dim3(512, 1, 1), 256, 0, stream>>>(
      Cb, Wob, Wob, Wob, out, out, nullptr, bo, MTOT, D_MODEL, D_MODEL, 1, 1.0f);
}

// Round 10
// 243.861 us; speedup vs baseline: 1.1261x; 1.0181x over previous
//
#include <hip/hip_runtime.h>
#include <cstdint>
#include <cstddef>

// Problem constants (MultiHeadAttention: B=4, T=2048, d_model=1024, H=16, hd=64)
#define D_MODEL 1024
#define SEQQ    2048
#define NBATCH  4
#define NHEAD   16
#define HDIM    64
#define MTOT    (NBATCH * SEQQ)   // 8192 rows

typedef __attribute__((ext_vector_type(8))) short short8;   // 8 x bf16 (4 VGPRs) — MFMA A/B frag
typedef __attribute__((ext_vector_type(4))) float floatx4;  // MFMA C/D frag
typedef unsigned short u16;                                  // bf16 bits

__device__ __forceinline__ u16 f2bf(float f) {
  union { float f; uint32_t u; } a; a.f = f;
  uint32_t u = a.u;
  u += 0x7fffu + ((u >> 16) & 1u);   // RN-even
  return (u16)(u >> 16);
}

__device__ __forceinline__ floatx4 mfma16(short8 a, short8 b, floatx4 c) {
  return __builtin_amdgcn_mfma_f32_16x16x32_bf16(a, b, c, 0, 0, 0);
}

// async global->LDS, 16B per lane. LDS dest = wave-uniform base + lane*16.
__device__ __forceinline__ void load_lds16(const void* g, void* l) {
  __builtin_amdgcn_global_load_lds(
      (const __attribute__((address_space(1))) uint32_t*)g,
      (__attribute__((address_space(3))) uint32_t*)l, 16, 0, 0);
}

// ---------------------------------------------------------------- fused casts f32->bf16
// blocks [0, 8192): X. blocks [8192, 12288): weights, 1024 blocks each.
__global__ __launch_bounds__(256) void k_cast_all(
    const float* __restrict__ X, const float* __restrict__ w0,
    const float* __restrict__ w1, const float* __restrict__ w2,
    const float* __restrict__ w3,
    u16* __restrict__ xb, u16* __restrict__ y0, u16* __restrict__ y1,
    u16* __restrict__ y2, u16* __restrict__ y3) {
  const int bx = blockIdx.x;
  const float* src; u16* dst; int i;
  if (bx < 8192) {
    src = X; dst = xb; i = (bx * 256 + threadIdx.x) * 4;
  } else {
    const int w = (bx - 8192) >> 10;
    src = (w == 0) ? w0 : (w == 1) ? w1 : (w == 2) ? w2 : w3;
    dst = (w == 0) ? y0 : (w == 1) ? y1 : (w == 2) ? y2 : y3;
    i = (((bx - 8192) & 1023) * 256 + threadIdx.x) * 4;
  }
  float4 v = *(const float4*)(src + i);
  ushort4 o;
  o.x = f2bf(v.x); o.y = f2bf(v.y); o.z = f2bf(v.z); o.w = f2bf(v.w);
  *(ushort4*)(dst + i) = o;
}

// ---------------------------------------------------------------- GEMM  C = A @ B^T (+bias)
// r9 structure (measured: fell out of top-5): pipelined double-buffered K-loop
// + XCD/L2 remap. Untouched this round.
__global__ __launch_bounds__(256) void k_gemm_bt(
    const u16* __restrict__ A,
    const u16* __restrict__ B0, const u16* __restrict__ B1, const u16* __restrict__ B2,
    void* __restrict__ C0, void* __restrict__ C1, u16* __restrict__ VtOut,
    const float* __restrict__ bias, int M, int N, int K, int f32out, float ascaleQ) {
  __shared__ __align__(16) u16 As[2][128 * 64];
  __shared__ __align__(16) u16 Bs[2][128 * 64];
  const int tid = threadIdx.x;
  const int lane = tid & 63, wave = tid >> 6;
  const int quad = lane >> 4, l15 = lane & 15;

  // XCD/L2-aware remap. 512 blocks per z.
  const int bx = blockIdx.x;
  const int swz = (bx & 7) * 64 + (bx >> 3);
  const int m0 = (swz >> 3) * 128, n0 = (swz & 7) * 128;

  const int wr = wave >> 1, wc = wave & 1;
  const u16* Bm = (blockIdx.z == 0) ? B0 : (blockIdx.z == 1 ? B1 : B2);
  void* Cm = (blockIdx.z == 0) ? C0 : C1;
  const float ascale = (blockIdx.z == 0) ? ascaleQ : 1.0f;

  floatx4 acc[4][4];
#pragma unroll
  for (int i = 0; i < 4; ++i)
#pragma unroll
    for (int jj = 0; jj < 4; ++jj) acc[i][jj] = (floatx4){0.f, 0.f, 0.f, 0.f};

  const int srow = tid >> 3;                       // 0..31
  const int scolx = ((tid & 7) * 8) ^ ((srow & 7) * 8);  // swizzled source column
  const u16* Ag = A + (size_t)(m0 + srow) * K + scolx;
  const u16* Bg = Bm + (size_t)(n0 + srow) * K + scolx;

#define STAGE_AB(tt, buf)                                                            \
  {                                                                                  \
    const int kk_ = (tt) * 64;                                                       \
    _Pragma("unroll")                                                                \
    for (int p = 0; p < 4; ++p) {                                                    \
      load_lds16(Ag + (size_t)(p * 32) * K + kk_, &As[buf][p * 2048 + wave * 512]);  \
      load_lds16(Bg + (size_t)(p * 32) * K + kk_, &Bs[buf][p * 2048 + wave * 512]);  \
    }                                                                                \
  }

  const int nIt = K / 64;   // 16
  STAGE_AB(0, 0);           // prologue: first tile in flight

  for (int it = 0; it < nIt; ++it) {
    const int cur = it & 1;
    __syncthreads();                      // drains stage(it); prior reads of buf[cur^1] done
    if (it + 1 < nIt) STAGE_AB(it + 1, cur ^ 1);   // overlaps compute(it)

    short8 af[2][4], bfg[2][4];
#pragma unroll
    for (int ks = 0; ks < 2; ++ks) {
      const int kkx = (ks * 32 + quad * 8) ^ ((l15 & 7) * 8);
#pragma unroll
      for (int i = 0; i < 4; ++i) {
        af[ks][i]  = *(const short8*)&As[cur][(wr * 64 + i * 16 + l15) * 64 + kkx];
        bfg[ks][i] = *(const short8*)&Bs[cur][(wc * 64 + i * 16 + l15) * 64 + kkx];
      }
    }
#pragma unroll
    for (int ks = 0; ks < 2; ++ks)
#pragma unroll
      for (int mi = 0; mi < 4; ++mi)
#pragma unroll
        for (int ni = 0; ni < 4; ++ni)
          acc[mi][ni] = mfma16(af[ks][mi], bfg[ks][ni], acc[mi][ni]);
  }
#undef STAGE_AB

  // Epilogue. C/D layout: col = lane&15, row = quad*4 + reg (m89-verified).
  if (blockIdx.z == 2) {
    // transposed V write: Vt[(b*16+h)*64 + d][t], 4 regs = t..t+3 contiguous
#pragma unroll
    for (int mi = 0; mi < 4; ++mi) {
#pragma unroll
      for (int ni = 0; ni < 4; ++ni) {
        const int row = m0 + wr * 64 + mi * 16 + quad * 4;   // token
        const int col = n0 + wc * 64 + ni * 16 + l15;        // channel
        const int b = row >> 11, t = row & 2047;
        const int h = col >> 6, d = col & 63;
        ushort4 pk;
        pk.x = f2bf(acc[mi][ni][0]); pk.y = f2bf(acc[mi][ni][1]);
        pk.z = f2bf(acc[mi][ni][2]); pk.w = f2bf(acc[mi][ni][3]);
        *(ushort4*)(VtOut + (((size_t)(b * 16 + h) * 64 + d) * SEQQ + t)) = pk;
      }
    }
    return;
  }
#pragma unroll
  for (int mi = 0; mi < 4; ++mi) {
#pragma unroll
    for (int ni = 0; ni < 4; ++ni) {
      const int row = m0 + wr * 64 + mi * 16 + quad * 4;
      const int col = n0 + wc * 64 + ni * 16 + l15;
      const float bv = bias ? bias[col] : 0.f;
#pragma unroll
      for (int r = 0; r < 4; ++r) {
        const float v = acc[mi][ni][r] * ascale + bv;
        if (f32out) ((float*)Cm)[(size_t)(row + r) * N + col] = v;
        else        ((u16*)Cm)[(size_t)(row + r) * N + col] = f2bf(v);
      }
    }
  }
}

// ---------------------------------------------------------------- flash attention
// ROUND-10: LDS-port roofline fix. r9 closed arithmetic: per CU-iter the 16
// resident waves issue 512 ds_read_b128 = ~6144 cyc of LDS-port demand vs
// 6960 measured -> ~88% LDS-saturated. Each b128 fed only 2 MFMAs (2 q-tiles
// per wave). THIS ROUND: 4 q-tiles per wave (two pairs (p,31-p),(p+8,23-p))
// -> 4 MFMAs per b128, halving LDS demand per unit work. 256-thread blocks,
// 4 waves (s=wave gives the 16-row subtile), 512 blocks; per-CU pairing j vs
// 7-j keeps Sum(nSub)=57 constant; per-wave active work = 33+33 = 66 for
// every wave (pair sums constant). launch_bounds(256,2) caps VGPR at 256 ->
// 2 blocks/CU (est. usage ~230, margin ok; WRITE_SIZE is the spill tripwire).
// Keeps: KVBLK=128 dbuf, permlane P-transpose, setprio, XOR-8 staging swizzles.
__device__ __forceinline__ short8 mk8(uint32_t a, uint32_t b, uint32_t c, uint32_t d) {
  union { uint32_t u[4]; short8 s; } t;
  t.u[0] = a; t.u[1] = b; t.u[2] = c; t.u[3] = d;
  return t.s;
}

__device__ __forceinline__ void softmax_reg(
    const floatx4 (&st)[4], float& lp, uint32_t (&w)[4][2]) {
#pragma unroll
  for (int ni = 0; ni < 4; ++ni) {
    const float p0 = __builtin_amdgcn_exp2f(st[ni][0]);
    const float p1 = __builtin_amdgcn_exp2f(st[ni][1]);
    const float p2 = __builtin_amdgcn_exp2f(st[ni][2]);
    const float p3 = __builtin_amdgcn_exp2f(st[ni][3]);
    lp += (p0 + p1) + (p2 + p3);
    w[ni][0] = __builtin_amdgcn_perm(__float_as_uint(p1), __float_as_uint(p0), 0x07060302u);
    w[ni][1] = __builtin_amdgcn_perm(__float_as_uint(p3), __float_as_uint(p2), 0x07060302u);
  }
}

// PV A-operand (keys kc*32+quad*8+{0..7} at q=l15) via quad-transpose swaps.
__device__ __forceinline__ short8 pf_prep(const uint32_t (&w)[4][2], int kc) {
  uint32_t y0 = w[2 * kc][0], z0 = w[2 * kc + 1][0];
  asm("v_permlane32_swap_b32 %0, %1" : "+v"(y0), "+v"(z0));
  asm("v_permlane16_swap_b32 %0, %1" : "+v"(y0), "+v"(z0));
  uint32_t y1 = w[2 * kc][1], z1 = w[2 * kc + 1][1];
  asm("v_permlane32_swap_b32 %0, %1" : "+v"(y1), "+v"(z1));
  asm("v_permlane16_swap_b32 %0, %1" : "+v"(y1), "+v"(z1));
  return mk8(y0, y1, z0, z1);
}

__global__ __launch_bounds__(256, 2) void k_attn(
    const u16* __restrict__ Q, const u16* __restrict__ Kg,
    const u16* __restrict__ Vt, u16* __restrict__ O) {
  __shared__ __align__(16) u16 Ks[2][128 * 64];   // [key 0..127][d 0..63]
  __shared__ __align__(16) u16 Vs[2][64 * 128];   // [d 0..63][key 0..127]
  const int tid = threadIdx.x, lane = tid & 63, wave = tid >> 6;
  const int quad = lane >> 4, l15 = lane & 15;

  // balanced (j, bh): CU c hosts blocks c and c+256 -> j and 7-j
  // -> per-CU Sum(nSub) = (32-j)+(25+j) = 57, constant.
  const int lin = blockIdx.x;
  const int c = lin & 255, k2 = lin >> 8;
  const int j = k2 ? (7 - (c & 7)) : (c & 7);       // 0..7
  const int bh = (c >> 3) | (k2 << 5);              // 0..63
  const int b = bh >> 4, h = bh & 15;

  const int s = wave;                 // 16-row subtile 0..3
  const int p1 = j, p2 = j + 8;       // this block's two pairs
  int lim[4], qw[4];
  lim[0] = p1;      qw[0] = 64 * p1 + 16 * s;
  lim[1] = 31 - p1; qw[1] = SEQQ - 64 * (p1 + 1) + 16 * s;
  lim[2] = p2;      qw[2] = 64 * p2 + 16 * s;
  lim[3] = 31 - p2; qw[3] = SEQQ - 64 * (p2 + 1) + 16 * s;
  const int nSub = 32 - j;            // 64-key sub-iterations
  const int nT = (nSub + 1) >> 1;     // 128-key tiles

  const u16* kbase = Kg + (size_t)(b * SEQQ) * D_MODEL + h * HDIM;
  const u16* vbase = Vt + (size_t)bh * (HDIM * SEQQ);

  // staging (256 threads): K rows via tid>>3 (0..31, 4 calls x 32 rows);
  // V rows via tid>>4 (0..15, 4 calls x 16 rows). XOR-8 pre-swizzled source.
  const int krow = tid >> 3;
  const int kcol = ((tid & 7) * 8) ^ ((krow & 7) * 8);
  const int vrow = tid >> 4, vslot = tid & 15;
  const int vcol = (vslot >> 3) * 64 + (((vslot & 7) ^ (vrow & 7)) * 8);

#define STAGE_KV(tt, buf)                                                           \
  {                                                                                 \
    const int kt_ = (tt) * 128;                                                     \
    _Pragma("unroll")                                                               \
    for (int c4 = 0; c4 < 4; ++c4)                                                  \
      load_lds16(kbase + (size_t)(kt_ + c4 * 32 + krow) * D_MODEL + kcol,           \
                 &Ks[buf][c4 * 2048 + wave * 512]);                                 \
    _Pragma("unroll")                                                               \
    for (int c4 = 0; c4 < 4; ++c4)                                                  \
      load_lds16(vbase + (size_t)(c4 * 16 + vrow) * SEQQ + kt_ + vcol,              \
                 &Vs[buf][c4 * 2048 + wave * 512]);                                 \
  }

  STAGE_KV(0, 0);   // first tile in flight before anything else

  // Q fragments for all 4 tiles ([idx=l15][k=quad*8+jj]); Q pre-scaled.
  short8 qf[4][2];
#pragma unroll
  for (int t4 = 0; t4 < 4; ++t4) {
    const u16* qp = Q + (size_t)(b * SEQQ + qw[t4] + l15) * D_MODEL + h * HDIM;
#pragma unroll
    for (int ks = 0; ks < 2; ++ks)
      qf[t4][ks] = *(const short8*)(qp + ks * 32 + quad * 8);
  }

  floatx4 acc[4][4];
  float lp[4] = {0.f, 0.f, 0.f, 0.f};
#pragma unroll
  for (int t4 = 0; t4 < 4; ++t4)
#pragma unroll
    for (int i = 0; i < 4; ++i) acc[t4][i] = (floatx4){0.f, 0.f, 0.f, 0.f};

  for (int t = 0; t < nT; ++t) {
    const int cur = t & 1;
    __syncthreads();   // drains stage(t) (vmcnt) + all reads of buf[cur^1]
    if (t + 1 < nT) STAGE_KV(t + 1, cur ^ 1);   // overlaps compute(t)

#pragma unroll
    for (int sub = 0; sub < 2; ++sub) {
      const int u = 2 * t + sub;       // 64-key tile index

      // batched K fragment loads ([key=l15][d=quad*8+jj])
      short8 kf[4][2];
#pragma unroll
      for (int ni = 0; ni < 4; ++ni)
#pragma unroll
        for (int ks = 0; ks < 2; ++ks)
          kf[ni][ks] = *(const short8*)&Ks[cur][(sub * 64 + ni * 16 + l15) * 64 +
                                               ((ks * 32 + quad * 8) ^ ((l15 & 7) * 8))];

      uint32_t w[4][4][2];   // [tile][ni][slot]
      bool act[4];
#pragma unroll
      for (int t4 = 0; t4 < 4; ++t4) {
        act[t4] = (u <= lim[t4]);      // block-uniform
        if (act[t4]) {
          floatx4 st[4];   // S^T: row=key (quad*4+r, tile ni), col=q (l15)
          __builtin_amdgcn_s_setprio(1);
#pragma unroll
          for (int ni = 0; ni < 4; ++ni) {
            floatx4 sv = (floatx4){0.f, 0.f, 0.f, 0.f};
            sv = mfma16(kf[ni][0], qf[t4][0], sv);
            sv = mfma16(kf[ni][1], qf[t4][1], sv);
            st[ni] = sv;
          }
          __builtin_amdgcn_s_setprio(0);
          if (u == lim[t4]) {   // diagonal tile: mask key > q (position-generic)
            const int qg = qw[t4] + l15;
#pragma unroll
            for (int ni = 0; ni < 4; ++ni) {
              const int kg = u * 64 + ni * 16 + quad * 4;
#pragma unroll
              for (int r = 0; r < 4; ++r)
                if (kg + r > qg) st[ni][r] = -1e30f;
            }
          }
          softmax_reg(st, lp[t4], w[t4]);
        }
      }

      // batched V fragment loads ([d=l15][key=quad*8+jj]); shared by all tiles
      short8 vf[2][4];
#pragma unroll
      for (int kc = 0; kc < 2; ++kc)
#pragma unroll
        for (int di = 0; di < 4; ++di)
          vf[kc][di] = *(const short8*)&Vs[cur][(di * 16 + l15) * 128 + sub * 64 +
                                               ((kc * 32 + quad * 8) ^ ((l15 & 7) * 8))];

#pragma unroll
      for (int kc = 0; kc < 2; ++kc) {
#pragma unroll
        for (int t4 = 0; t4 < 4; ++t4) {
          if (act[t4]) {
            const short8 pf = pf_prep(w[t4], kc);
            __builtin_amdgcn_s_setprio(1);
#pragma unroll
            for (int di = 0; di < 4; ++di)
              acc[t4][di] = mfma16(pf, vf[kc][di], acc[t4][di]);
            __builtin_amdgcn_s_setprio(0);
          }
        }
      }
    }
  }

  // epilogue per tile: l reduce across quads, then O rows q=quad*4+r
#pragma unroll
  for (int t4 = 0; t4 < 4; ++t4) {
    float l = lp[t4];
    l += __shfl_xor(l, 16); l += __shfl_xor(l, 32);
    u16* orow = O + (size_t)(b * SEQQ + qw[t4] + quad * 4) * D_MODEL + h * HDIM + l15;
#pragma unroll
    for (int r = 0; r < 4; ++r) {
      const float inv = 1.0f / __shfl(l, quad * 4 + r, 16);
#pragma unroll
      for (int di = 0; di < 4; ++di)
        orow[(size_t)r * D_MODEL + di * 16] = f2bf(acc[t4][di][r] * inv);
    }
  }
}

// ---------------------------------------------------------------- launch
extern "C" void kernel_launch(void* const* d_in, const int* in_sizes, int n_in,
                              void* d_out, int out_size, void* d_ws, size_t ws_size,
                              hipStream_t stream) {
  const float* X  = (const float*)d_in[0];
  const float* Wq = (const float*)d_in[1];
  const float* Wk = (const float*)d_in[2];
  const float* Wv = (const float*)d_in[3];
  const float* Wo = (const float*)d_in[4];
  const float* bo = (const float*)d_in[5];
  float* out = (float*)d_out;

  u16* ws = (u16*)d_ws;
  const size_t NE = (size_t)MTOT * D_MODEL;    // 8,388,608
  u16* Xb  = ws;
  u16* Qb  = Xb + NE;
  u16* Kb  = Qb + NE;
  u16* Vt  = Kb + NE;          // V projection written directly transposed
  u16* Cb  = Vt + NE;
  u16* Wqb = Cb + NE;
  u16* Wkb = Wqb + (size_t)D_MODEL * D_MODEL;
  u16* Wvb = Wkb + (size_t)D_MODEL * D_MODEL;
  u16* Wob = Wvb + (size_t)D_MODEL * D_MODEL;

  const float SCL2E = 0.18033688f;   // (1/sqrt(64)) * log2(e), folded into Q

  // 1. all casts in one launch
  k_cast_all<<<12288, 256, 0, stream>>>(X, Wq, Wk, Wv, Wo, Xb, Wqb, Wkb, Wvb, Wob);

  // 2. fused QKV projections (Q pre-scaled; V written transposed into Vt)
  k_gemm_bt<<<dim3(512, 1, 3), 256, 0, stream>>>(
      Xb, Wqb, Wkb, Wvb, Qb, Kb, Vt, nullptr, MTOT, D_MODEL, D_MODEL, 0, SCL2E);

  // 3. causal flash attention, 4 q-tiles/wave, 4-wave blocks, balanced 1D grid
  k_attn<<<512, 256, 0, stream>>>(Qb, Kb, Vt, Cb);

  // 4. output projection + bias, f32 out
  k_gemm_bt<<<dim3(512, 1, 1), 256, 0, stream>>>(
      Cb, Wob, Wob, Wob, out, out, nullptr, bo, MTOT, D_MODEL, D_MODEL, 1, 1.0f);
}